// Round 2
// baseline (89.102 us; speedup 1.0000x reference)
//
#include <hip/hip_runtime.h>

// Problem constants (fixed by the reference setup)
#define B_ 128
#define N_ 65536
#define P_ 4096
#define T_ 32
#define D_ 2
#define K_ 4
#define S_ 16                      // slices per batch
#define PPB 256                    // pairs per block (P_/S_)
#define CHUNK (N_ / S_)            // fun-row floats each block stream-prefetches

// sorted-descending top-4 insert chain (7 ops)
#define INS(v0, v1, v2, v3, val)                                  \
    {                                                             \
        float _x = fminf(v0, val); v0 = fmaxf(v0, val);           \
        float _y = fminf(v1, _x);  v1 = fmaxf(v1, _x);            \
        float _z = fminf(v2, _y);  v2 = fmaxf(v2, _y);            \
        v3 = fmaxf(v3, _z);                                       \
    }

// ---------------------------------------------------------------------------
// R2: gather phase is latency-bound (random 4B HBM misses after the poison
// fill flushes L2/L3; only 16 waves/CU of MLP). Fixes:
//  - 2048 blocks x 256 thr, 1 pair/thread, __launch_bounds__(256,8)
//    -> 32 waves/CU (2x miss-level parallelism).
//  - cooperative L2-warm: each block streams its 16KB slice of the batch's
//    fun row (coalesced float4) so the XCD's L2 (4MB = 16 batches x 256KB)
//    absorbs the random gathers; gather misses merge with streaming misses.
//  - filter (d<=b dead pairs) + dim partition + broadcast b128 scan as in R1.
// ---------------------------------------------------------------------------
__global__ __launch_bounds__(256, 8) void fused_scan(
        const float* __restrict__ fun,
        const int* __restrict__ bidx,
        const int* __restrict__ didx,
        const int* __restrict__ pdim,
        float* __restrict__ partial) {
    __shared__ __align__(16) float2 bdS[PPB + 8];
    __shared__ int cnt0S[4];
    __shared__ int cnt1S[4];
    __shared__ __align__(16) float4 mrg[4][64];

    int bid   = blockIdx.x;               // 0..2047
    int xcd   = bid & 7;
    int seq   = bid >> 3;                 // 0..255
    int batch = xcd * 16 + (seq & 15);    // all 16 slices of a batch on one XCD
    int slice = seq >> 4;                 // 0..15

    int tid  = threadIdx.x;
    int lane = tid & 63;
    int wave = tid >> 6;

    const float* f = fun + (size_t)batch * N_;
    int p = batch * P_ + slice * PPB + tid;

    // --- coalesced index loads ---
    int bi = bidx[p];
    int di = didx[p];
    int pd = pdim[p];

    // --- streaming L2-warm prefetch of this block's chunk of the fun row ---
    const float4* pf = (const float4*)(f + slice * CHUNK);
    float4 w0 = pf[tid];
    float4 w1 = pf[tid + 256];
    float4 w2 = pf[tid + 512];
    float4 w3 = pf[tid + 768];

    // --- random gathers (race with / piggyback on the streaming fetches) ---
    float b = f[bi], d = f[di];

    // --- filter (d > b) + partition by dim via ballot compaction ---
    bool k0 = (d > b) && (pd == 0);
    bool k1 = (d > b) && (pd == 1);
    unsigned long long bal0 = __ballot(k0);
    unsigned long long bal1 = __ballot(k1);
    if (lane == 0) {
        cnt0S[wave] = __popcll(bal0);
        cnt1S[wave] = __popcll(bal1);
    }

    // keep prefetch loads live (anti-DCE, guide rule #17); gathers are
    // already issued, so the waitcnt here overlaps with them
    float ka = (w0.x + w0.y + w0.z + w0.w) + (w1.x + w1.y + w1.z + w1.w)
             + (w2.x + w2.y + w2.z + w2.w) + (w3.x + w3.y + w3.z + w3.w);
    asm volatile("" :: "v"(ka));

    __syncthreads();

    int pre0 = 0, pre1 = 0, tot0 = 0, tot1 = 0;
    #pragma unroll
    for (int c = 0; c < 4; ++c) {
        int c0 = cnt0S[c], c1 = cnt1S[c];
        if (c < wave) { pre0 += c0; pre1 += c1; }
        tot0 += c0; tot1 += c1;
    }
    int A  = (tot0 + 3) & ~3;             // dim0 segment padded to x4
    int L1 = (tot1 + 3) & ~3;             // dim1 segment padded to x4

    unsigned long long lm = (1ull << lane) - 1ull;
    if (k0) bdS[pre0 + __popcll(bal0 & lm)]     = make_float2(b, d);
    if (k1) bdS[A + pre1 + __popcll(bal1 & lm)] = make_float2(b, d);
    // sentinel padding (tent always negative): threads 0-2 pad seg0, 4-6 seg1
    if (tid < A - tot0)                  bdS[tot0 + tid]           = make_float2(4.f, -4.f);
    if (tid >= 4 && tid - 4 < L1 - tot1) bdS[A + tot1 + (tid - 4)] = make_float2(4.f, -4.f);
    __syncthreads();

    // --- scan: four same-dim pairs per wave iteration, one b128 per half ---
    int half = lane >> 5;
    int t    = lane & 31;
    float tf = (float)(t + 1) * 0.03125f; // tseq[t], exact in fp32

    float a0 = 0.f, a1 = 0.f, a2 = 0.f, a3 = 0.f;  // dim0 partial top-4
    float c0 = 0.f, c1 = 0.f, c2 = 0.f, c3 = 0.f;  // dim1 partial top-4

    const float2* bd0 = bdS + 2 * half;
    #pragma unroll 2
    for (int j = wave * 4; j < A; j += 16) {
        float4 q = *(const float4*)(bd0 + j);
        float v0 = fminf(tf - q.x, q.y - tf);
        float v1 = fminf(tf - q.z, q.w - tf);
        INS(a0, a1, a2, a3, v0);
        INS(a0, a1, a2, a3, v1);
    }
    #pragma unroll 2
    for (int j = wave * 4; j < L1; j += 16) {
        float4 q = *(const float4*)(bd0 + A + j);
        float v0 = fminf(tf - q.x, q.y - tf);
        float v1 = fminf(tf - q.z, q.w - tf);
        INS(c0, c1, c2, c3, v0);
        INS(c0, c1, c2, c3, v1);
    }

    // --- even/odd half merge: partner lane l^32 holds same (t, dim) work ---
    float u0 = (half == 0) ? a0 : c0, x0 = (half == 0) ? c0 : a0;
    float u1 = (half == 0) ? a1 : c1, x1 = (half == 0) ? c1 : a1;
    float u2 = (half == 0) ? a2 : c2, x2 = (half == 0) ? c2 : a2;
    float u3 = (half == 0) ? a3 : c3, x3 = (half == 0) ? c3 : a3;
    float q;
    q = __shfl_xor(x0, 32); INS(u0, u1, u2, u3, q);
    q = __shfl_xor(x1, 32); INS(u0, u1, u2, u3, q);
    q = __shfl_xor(x2, 32); INS(u0, u1, u2, u3, q);
    q = __shfl_xor(x3, 32); INS(u0, u1, u2, u3, q);
    // lane l now holds top-4 for combo = l (dim = l>>5, t = l&31)

    mrg[wave][lane] = make_float4(u0, u1, u2, u3);
    __syncthreads();

    if (wave == 0) {
        float v0 = 0.f, v1 = 0.f, v2 = 0.f, v3 = 0.f;
        #pragma unroll
        for (int w = 0; w < 4; ++w) {
            float4 m = mrg[w][lane];
            INS(v0, v1, v2, v3, m.x);
            INS(v0, v1, v2, v3, m.y);
            INS(v0, v1, v2, v3, m.z);
            INS(v0, v1, v2, v3, m.w);
        }
        ((float4*)partial)[((size_t)batch * S_ + slice) * 64 + lane] =
            make_float4(v0, v1, v2, v3);
    }
}

// ---------------------------------------------------------------------------
// Fold the 16 slice-partials per (batch, combo) into the final top-4.
// out index = batch*256 + combo*4 + k matches reference [B, D, T, K].
// ---------------------------------------------------------------------------
__global__ __launch_bounds__(256) void final_merge(
        const float* __restrict__ partial,
        float* __restrict__ out) {
    int tid   = blockIdx.x * 256 + threadIdx.x; // 0 .. B_*64-1
    int batch = tid >> 6;
    int combo = tid & 63;
    const float4* src = (const float4*)partial + (size_t)batch * S_ * 64 + combo;
    float v0 = 0.f, v1 = 0.f, v2 = 0.f, v3 = 0.f;
    #pragma unroll
    for (int s = 0; s < S_; ++s) {
        float4 p = src[(size_t)s * 64];
        INS(v0, v1, v2, v3, p.x);
        INS(v0, v1, v2, v3, p.y);
        INS(v0, v1, v2, v3, p.z);
        INS(v0, v1, v2, v3, p.w);
    }
    ((float4*)out)[tid] = make_float4(v0, v1, v2, v3);
}

extern "C" void kernel_launch(void* const* d_in, const int* in_sizes, int n_in,
                              void* d_out, int out_size, void* d_ws, size_t ws_size,
                              hipStream_t stream) {
    const float* fun  = (const float*)d_in[0]; // [B, N] f32
    const int*   bidx = (const int*)d_in[1];   // [B, P] i32
    const int*   didx = (const int*)d_in[2];   // [B, P] i32
    const int*   pdim = (const int*)d_in[3];   // [B, P] i32
    float* out = (float*)d_out;                // [B, D, T, K] f32

    float* partial = (float*)d_ws;             // B*S*64*4 f32 = 2 MB

    fused_scan<<<B_ * S_, 256, 0, stream>>>(fun, bidx, didx, pdim, partial);
    final_merge<<<(B_ * 64) / 256, 256, 0, stream>>>(partial, out);
}

// Round 3
// 89.096 us; speedup vs baseline: 1.0001x; 1.0001x over previous
//
#include <hip/hip_runtime.h>

// Problem constants (fixed by the reference setup)
#define B_ 128
#define N_ 65536
#define P_ 4096
#define T_ 32
#define D_ 2
#define K_ 4
#define S_ 16                      // slices per batch
#define PPB 256                    // pairs per block (P_/S_)
#define CHUNK (N_ / S_)            // fun-row floats each block stream-prefetches

// sorted-descending top-4 insert chain (7 ops)
#define INS(v0, v1, v2, v3, val)                                  \
    {                                                             \
        float _x = fminf(v0, val); v0 = fmaxf(v0, val);           \
        float _y = fminf(v1, _x);  v1 = fmaxf(v1, _x);            \
        float _z = fminf(v2, _y);  v2 = fmaxf(v2, _y);            \
        v3 = fmaxf(v3, _z);                                       \
    }

// ---------------------------------------------------------------------------
// R3: phase-ordered cache warm. The poison fill flushes L2+L3 every
// iteration, so the 1M random 4B gathers from fun are cold HBM line
// fetches (the real cost). R2's prefetch raced with the gathers (in-order
// vmcnt: gathers only waited for their index load). Now:
//   phase A: stream-prefetch the block's 16 KB chunk of its batch's fun row
//            (grid covers all 33 MB exactly once) + index loads.
//   phase B: CONSUME the prefetch (forces vmcnt(0): lines are in L2/L3),
//            __syncthreads + sched_barrier(0) so gathers cannot be hoisted.
//   phase C: random gathers -> now L2 hits (own XCD holds its 16 batch rows
//            = 4 MB) or L3 hits (memory-side, holds all of fun).
// Then: filter dead pairs (d<=b), ballot partition by dim, broadcast-b128
// scan, shfl/LDS merge (unchanged from R2, verified absmax=0).
// ---------------------------------------------------------------------------
__global__ __launch_bounds__(256, 8) void fused_scan(
        const float* __restrict__ fun,
        const int* __restrict__ bidx,
        const int* __restrict__ didx,
        const int* __restrict__ pdim,
        float* __restrict__ partial) {
    __shared__ __align__(16) float2 bdS[PPB + 8];
    __shared__ int cnt0S[4];
    __shared__ int cnt1S[4];
    __shared__ __align__(16) float4 mrg[4][64];

    int bid   = blockIdx.x;               // 0..2047
    int xcd   = bid & 7;
    int seq   = bid >> 3;                 // 0..255
    int batch = xcd * 16 + (seq & 15);    // all 16 slices of a batch on one XCD
    int slice = seq >> 4;                 // 0..15

    int tid  = threadIdx.x;
    int lane = tid & 63;
    int wave = tid >> 6;

    const float* f = fun + (size_t)batch * N_;
    int p = batch * P_ + slice * PPB + tid;

    // --- phase A: issue streaming prefetch FIRST (long pole), then indices ---
    const float4* pf = (const float4*)(f + slice * CHUNK);
    float4 w0 = pf[tid];
    float4 w1 = pf[tid + 256];
    float4 w2 = pf[tid + 512];
    float4 w3 = pf[tid + 768];
    int bi = bidx[p];
    int di = didx[p];
    int pd = pdim[p];

    // --- phase B: consume prefetch (vmcnt drain -> lines resident), sync ---
    float ka = (w0.x + w0.y + w0.z + w0.w) + (w1.x + w1.y + w1.z + w1.w)
             + (w2.x + w2.y + w2.z + w2.w) + (w3.x + w3.y + w3.z + w3.w);
    asm volatile("" :: "v"(ka));          // keep loads live (anti-DCE)
    __syncthreads();                      // whole block's chunk is warm
    __builtin_amdgcn_sched_barrier(0);    // forbid hoisting gathers above

    // --- phase C: random gathers, now cache-warm ---
    float b = f[bi], d = f[di];

    // --- filter (d > b) + partition by dim via ballot compaction ---
    bool k0 = (d > b) && (pd == 0);
    bool k1 = (d > b) && (pd == 1);
    unsigned long long bal0 = __ballot(k0);
    unsigned long long bal1 = __ballot(k1);
    if (lane == 0) {
        cnt0S[wave] = __popcll(bal0);
        cnt1S[wave] = __popcll(bal1);
    }
    __syncthreads();

    int pre0 = 0, pre1 = 0, tot0 = 0, tot1 = 0;
    #pragma unroll
    for (int c = 0; c < 4; ++c) {
        int c0 = cnt0S[c], c1 = cnt1S[c];
        if (c < wave) { pre0 += c0; pre1 += c1; }
        tot0 += c0; tot1 += c1;
    }
    int A  = (tot0 + 3) & ~3;             // dim0 segment padded to x4
    int L1 = (tot1 + 3) & ~3;             // dim1 segment padded to x4

    unsigned long long lm = (1ull << lane) - 1ull;
    if (k0) bdS[pre0 + __popcll(bal0 & lm)]     = make_float2(b, d);
    if (k1) bdS[A + pre1 + __popcll(bal1 & lm)] = make_float2(b, d);
    // sentinel padding (tent always negative): threads 0-2 pad seg0, 4-6 seg1
    if (tid < A - tot0)                  bdS[tot0 + tid]           = make_float2(4.f, -4.f);
    if (tid >= 4 && tid - 4 < L1 - tot1) bdS[A + tot1 + (tid - 4)] = make_float2(4.f, -4.f);
    __syncthreads();

    // --- scan: four same-dim pairs per wave iteration, one b128 per half ---
    int half = lane >> 5;
    int t    = lane & 31;
    float tf = (float)(t + 1) * 0.03125f; // tseq[t], exact in fp32

    float a0 = 0.f, a1 = 0.f, a2 = 0.f, a3 = 0.f;  // dim0 partial top-4
    float c0 = 0.f, c1 = 0.f, c2 = 0.f, c3 = 0.f;  // dim1 partial top-4

    const float2* bd0 = bdS + 2 * half;
    #pragma unroll 2
    for (int j = wave * 4; j < A; j += 16) {
        float4 q = *(const float4*)(bd0 + j);
        float v0 = fminf(tf - q.x, q.y - tf);
        float v1 = fminf(tf - q.z, q.w - tf);
        INS(a0, a1, a2, a3, v0);
        INS(a0, a1, a2, a3, v1);
    }
    #pragma unroll 2
    for (int j = wave * 4; j < L1; j += 16) {
        float4 q = *(const float4*)(bd0 + A + j);
        float v0 = fminf(tf - q.x, q.y - tf);
        float v1 = fminf(tf - q.z, q.w - tf);
        INS(c0, c1, c2, c3, v0);
        INS(c0, c1, c2, c3, v1);
    }

    // --- even/odd half merge: partner lane l^32 holds same (t, dim) work ---
    float u0 = (half == 0) ? a0 : c0, x0 = (half == 0) ? c0 : a0;
    float u1 = (half == 0) ? a1 : c1, x1 = (half == 0) ? c1 : a1;
    float u2 = (half == 0) ? a2 : c2, x2 = (half == 0) ? c2 : a2;
    float u3 = (half == 0) ? a3 : c3, x3 = (half == 0) ? c3 : a3;
    float q;
    q = __shfl_xor(x0, 32); INS(u0, u1, u2, u3, q);
    q = __shfl_xor(x1, 32); INS(u0, u1, u2, u3, q);
    q = __shfl_xor(x2, 32); INS(u0, u1, u2, u3, q);
    q = __shfl_xor(x3, 32); INS(u0, u1, u2, u3, q);
    // lane l now holds top-4 for combo = l (dim = l>>5, t = l&31)

    mrg[wave][lane] = make_float4(u0, u1, u2, u3);
    __syncthreads();

    if (wave == 0) {
        float v0 = 0.f, v1 = 0.f, v2 = 0.f, v3 = 0.f;
        #pragma unroll
        for (int w = 0; w < 4; ++w) {
            float4 m = mrg[w][lane];
            INS(v0, v1, v2, v3, m.x);
            INS(v0, v1, v2, v3, m.y);
            INS(v0, v1, v2, v3, m.z);
            INS(v0, v1, v2, v3, m.w);
        }
        ((float4*)partial)[((size_t)batch * S_ + slice) * 64 + lane] =
            make_float4(v0, v1, v2, v3);
    }
}

// ---------------------------------------------------------------------------
// Fold the 16 slice-partials per (batch, combo) into the final top-4.
// out index = batch*256 + combo*4 + k matches reference [B, D, T, K].
// ---------------------------------------------------------------------------
__global__ __launch_bounds__(256) void final_merge(
        const float* __restrict__ partial,
        float* __restrict__ out) {
    int tid   = blockIdx.x * 256 + threadIdx.x; // 0 .. B_*64-1
    int batch = tid >> 6;
    int combo = tid & 63;
    const float4* src = (const float4*)partial + (size_t)batch * S_ * 64 + combo;
    float v0 = 0.f, v1 = 0.f, v2 = 0.f, v3 = 0.f;
    #pragma unroll
    for (int s = 0; s < S_; ++s) {
        float4 p = src[(size_t)s * 64];
        INS(v0, v1, v2, v3, p.x);
        INS(v0, v1, v2, v3, p.y);
        INS(v0, v1, v2, v3, p.z);
        INS(v0, v1, v2, v3, p.w);
    }
    ((float4*)out)[tid] = make_float4(v0, v1, v2, v3);
}

extern "C" void kernel_launch(void* const* d_in, const int* in_sizes, int n_in,
                              void* d_out, int out_size, void* d_ws, size_t ws_size,
                              hipStream_t stream) {
    const float* fun  = (const float*)d_in[0]; // [B, N] f32
    const int*   bidx = (const int*)d_in[1];   // [B, P] i32
    const int*   didx = (const int*)d_in[2];   // [B, P] i32
    const int*   pdim = (const int*)d_in[3];   // [B, P] i32
    float* out = (float*)d_out;                // [B, D, T, K] f32

    float* partial = (float*)d_ws;             // B*S*64*4 f32 = 2 MB

    fused_scan<<<B_ * S_, 256, 0, stream>>>(fun, bidx, didx, pdim, partial);
    final_merge<<<(B_ * 64) / 256, 256, 0, stream>>>(partial, out);
}